// Round 9
// baseline (510.504 us; speedup 1.0000x reference)
//
#include <hip/hip_runtime.h>
#include <math.h>
#include <stdint.h>

#define BB 256
#define C_IN 7
#define TT 160
#define PATCH 10
#define D_MODEL 512
#define L_TOK 16
#define D_INNER 1024
#define D_STATE 16
#define DT_RANK 32
#define EPS 1e-5f
#define NROWS (BB*L_TOK)   // 4096
#define KPAD 96            // 70 padded to 3*32

typedef __bf16 bf16x8 __attribute__((ext_vector_type(8)));
typedef __bf16 bf16x4 __attribute__((ext_vector_type(4)));
typedef float  f32x4  __attribute__((ext_vector_type(4)));

__device__ __forceinline__ float siluf(float x){ return x / (1.f + __expf(-x)); }
__device__ __forceinline__ float softplusf(float x){ return (x > 20.f) ? x : log1pf(__expf(x)); }

__device__ __forceinline__ void gload_lds16(const void* gp, void* lp){
  __builtin_amdgcn_global_load_lds(
      (const __attribute__((address_space(1))) unsigned int*)(uintptr_t)gp,
      (__attribute__((address_space(3))) unsigned int*)(uintptr_t)lp, 16, 0, 0);
}

__device__ __forceinline__ float block_reduce_sum(float v, float* sred4){
  for(int off=32; off>0; off>>=1) v += __shfl_down(v, off, 64);
  int lane = threadIdx.x & 63, wid = threadIdx.x >> 6;
  if(lane==0) sred4[wid] = v;
  __syncthreads();
  if(threadIdx.x==0) sred4[0] = sred4[0]+sred4[1]+sred4[2]+sred4[3];
  __syncthreads();
  float r = sred4[0];
  __syncthreads();
  return r;
}

// ---------------------------------------------------------------------------
// transpose + fp32->bf16: in [z][K][N] f32 -> out [z][N][K] bf16
// ---------------------------------------------------------------------------
__global__ __launch_bounds__(256) void transpose_bf16_kernel(
    const float* __restrict__ in, __bf16* __restrict__ out, int K, int N)
{
  __shared__ float tile[32][33];
  size_t moff = (size_t)blockIdx.z * K * N;
  int n0 = blockIdx.x*32, k0 = blockIdx.y*32;
  int tx = threadIdx.x, ty = threadIdx.y;
  #pragma unroll
  for(int rr=0;rr<4;rr++)
    tile[ty+rr*8][tx] = in[moff + (size_t)(k0+ty+rr*8)*N + n0+tx];
  __syncthreads();
  #pragma unroll
  for(int rr=0;rr<4;rr++)
    out[moff + (size_t)(n0+ty+rr*8)*K + k0+tx] = (__bf16)tile[tx][ty+rr*8];
}

// out_proj K-concat transpose: [layer][dir][1024][512] f32 -> [layer][512][2048] bf16
__global__ __launch_bounds__(256) void transpose_outw_kernel(
    const float* __restrict__ in, __bf16* __restrict__ out)
{
  __shared__ float tile[32][33];
  int z = blockIdx.z, layer = z>>1, dir = z&1;
  int n0 = blockIdx.x*32, k0 = blockIdx.y*32;
  int tx = threadIdx.x, ty = threadIdx.y;
  const float* ip = in + (size_t)z*1024*512;
  #pragma unroll
  for(int rr=0;rr<4;rr++)
    tile[ty+rr*8][tx] = ip[(size_t)(k0+ty+rr*8)*512 + n0+tx];
  __syncthreads();
  __bf16* op = out + (size_t)layer*512*2048 + (size_t)dir*1024;
  #pragma unroll
  for(int rr=0;rr<4;rr++)
    op[(size_t)(n0+ty+rr*8)*2048 + k0+tx] = (__bf16)tile[tx][ty+rr*8];
}

// ---------------------------------------------------------------------------
__global__ __launch_bounds__(256) void bn_patchify_kernel(
    const float* __restrict__ x, const float* __restrict__ bng,
    const float* __restrict__ bnb, const float* __restrict__ bnm,
    const float* __restrict__ bnv, __bf16* __restrict__ Abuf)
{
  int idx = blockIdx.x*256 + threadIdx.x;
  int row = idx / KPAD, k = idx % KPAD;
  int b = row >> 4, l = row & 15;
  float v = 0.f;
  if(k < C_IN*PATCH){
    int c = k / PATCH, j = k % PATCH;
    float xv = x[(b*C_IN + c)*TT + l*PATCH + j];
    v = (xv - bnm[c]) * rsqrtf(bnv[c] + EPS) * bng[c] + bnb[c];
  }
  Abuf[idx] = (__bf16)v;
}

__global__ __launch_bounds__(256) void cast_pad_pw_kernel(
    const float* __restrict__ pw, __bf16* __restrict__ pwb)
{
  int idx = blockIdx.x*256 + threadIdx.x;
  if(idx >= 512*KPAD) return;
  int n = idx / KPAD, k = idx % KPAD;
  pwb[idx] = (__bf16)(k < C_IN*PATCH ? pw[n*(C_IN*PATCH) + k] : 0.f);
}

// ---------------------------------------------------------------------------
// Generic MFMA bf16 GEMM (swapped-operand epilogue). EPI: 0 plain f32 (ACC
// optional); 1 dual f32+bf16; 2 bf16 softplus+bias; 3 bf16-only.
// ---------------------------------------------------------------------------
template<int BM, int BN, int BK, int ACC, int EPI>
__global__ __launch_bounds__(256) void mfma_gemm(
    const __bf16* __restrict__ A, const __bf16* __restrict__ Bt,
    float* __restrict__ C, __bf16* __restrict__ Cb,
    const float* __restrict__ bias, int N, int K, int lda, int ldb,
    size_t sA, size_t sB, size_t sC, size_t sBias)
{
  constexpr int NGA = BM/16, NGB = BN/16;
  constexpr int APW = NGA/4, BPW = NGB/4;
  constexpr int MI  = BM/32, FN  = BN/32;
  constexpr int NSL = BK/32;
  __shared__ __align__(16) __bf16 As[NSL*NGA*512];
  __shared__ __align__(16) __bf16 Bs[NSL*NGB*512];
  int z = blockIdx.z;
  A  += (size_t)z*sA;  Bt += (size_t)z*sB;
  if(EPI==0 || EPI==1) C  += (size_t)z*sC;
  if(EPI!=0)           Cb += (size_t)z*sC;
  if(EPI==2)           bias += (size_t)z*sBias;
  int tid  = threadIdx.x;
  int lane = tid & 63, w = tid >> 6;
  int wrow = w >> 1, wcol = w & 1;
  int r = lane & 15, q = lane >> 4;
  int row0 = blockIdx.y*BM, col0 = blockIdx.x*BN;

  f32x4 acc[MI][FN];
  #pragma unroll
  for(int i=0;i<MI;i++)
    #pragma unroll
    for(int j=0;j<FN;j++) acc[i][j] = (f32x4)0.f;

  const __bf16* aSrc[APW];
  #pragma unroll
  for(int g=0;g<APW;g++)
    aSrc[g] = A + (size_t)(row0 + (w*APW+g)*16 + r)*lda + q*8;
  const __bf16* bSrc[BPW];
  #pragma unroll
  for(int g=0;g<BPW;g++)
    bSrc[g] = Bt + (size_t)(col0 + (w*BPW+g)*16 + r)*ldb + q*8;

  for(int k0=0;k0<K;k0+=BK){
    #pragma unroll
    for(int s=0;s<NSL;s++){
      #pragma unroll
      for(int g=0;g<APW;g++)
        gload_lds16(aSrc[g] + k0 + s*32, As + (s*NGA + w*APW+g)*512);
      #pragma unroll
      for(int g=0;g<BPW;g++)
        gload_lds16(bSrc[g] + k0 + s*32, Bs + (s*NGB + w*BPW+g)*512);
    }
    __syncthreads();
    #pragma unroll
    for(int s=0;s<NSL;s++){
      bf16x8 aF[MI], bF[FN];
      #pragma unroll
      for(int i=0;i<MI;i++)
        aF[i] = *(const bf16x8*)(As + (s*NGA + wrow*MI+i)*512 + lane*8);
      #pragma unroll
      for(int j=0;j<FN;j++)
        bF[j] = *(const bf16x8*)(Bs + (s*NGB + wcol*FN+j)*512 + lane*8);
      #pragma unroll
      for(int i=0;i<MI;i++)
        #pragma unroll
        for(int j=0;j<FN;j++)
          acc[i][j] = __builtin_amdgcn_mfma_f32_16x16x32_bf16(bF[j], aF[i], acc[i][j], 0, 0, 0);
    }
    __syncthreads();
  }

  #pragma unroll
  for(int i=0;i<MI;i++){
    int m = row0 + wrow*(BM/2) + i*16 + r;
    #pragma unroll
    for(int j=0;j<FN;j++){
      int n = col0 + wcol*(BN/2) + j*16 + q*4;
      if(EPI==2){
        const float* bp = bias + n;
        bf16x4 hv;
        #pragma unroll
        for(int p=0;p<4;p++) hv[p] = (__bf16)softplusf(acc[i][j][p] + bp[p]);
        *(bf16x4*)(Cb + (size_t)m*N + n) = hv;
      } else if(EPI==3){
        bf16x4 hv;
        #pragma unroll
        for(int p=0;p<4;p++) hv[p] = (__bf16)acc[i][j][p];
        *(bf16x4*)(Cb + (size_t)m*N + n) = hv;
      } else {
        float* cp = C + (size_t)m*N + n;
        f32x4 ov = acc[i][j];
        if(ACC){
          f32x4 cv = *(const f32x4*)cp;
          #pragma unroll
          for(int p=0;p<4;p++) ov[p] += cv[p];
        }
        *(f32x4*)cp = ov;
        if(EPI==1){
          bf16x4 hv;
          #pragma unroll
          for(int p=0;p<4;p++) hv[p] = (__bf16)ov[p];
          *(bf16x4*)(Cb + (size_t)m*N + n) = hv;
        }
      }
    }
  }
}

// ---------------------------------------------------------------------------
// in_proj GEMM, BARRIER-FREE K-loop. M=4096, N=4096 (dirs concat), K=512.
// BM=128, BN=64, grid 64x32. The whole B tile (64x512 bf16 = 64 KB) is staged
// to LDS once (single barrier); each wave owns a 32-row band and streams its
// A fragments global->VGPR with a 1-slice software pipeline -- the 16-slice
// MFMA loop has no s_barrier and no vmcnt(0) drain, so loads overlap compute
// across the whole loop. Fused conv(4)+SiLU epilogue via lane shuffles.
// ---------------------------------------------------------------------------
__global__ __launch_bounds__(256) void mfma_inproj_conv(
    const __bf16* __restrict__ A, const __bf16* __restrict__ Bt,
    const float* __restrict__ cw, const float* __restrict__ cb,
    __bf16* __restrict__ ucb, __bf16* __restrict__ szb)
{
  constexpr int K = 512;
  __shared__ __align__(16) __bf16 Bs[16*4*512];   // 64 KB [slice][group][512]
  __shared__ float4 s_w4[64];
  __shared__ float  s_b[64];
  int tid  = threadIdx.x;
  int lane = tid & 63, w = tid >> 6;
  int r = lane & 15, q = lane >> 4;

  // XCD-band swizzle (harmless; keeps each XCD's B band L2-resident)
  int lin  = blockIdx.x + gridDim.x*blockIdx.y;   // gridDim.x = 64
  int xcd  = lin & 7;
  int idx  = lin >> 3;
  int colb = xcd*8 + (idx & 7);
  int rowb = idx >> 3;
  int row0 = rowb*128, col0 = colb*64;

  int dirq = col0 >> 11;
  int feat0 = col0 & 2047;
  bool is_u = feat0 < 1024;
  int dblk = col0 & 1023;
  if(is_u && tid < 64){
    s_w4[tid] = ((const float4*)(cw + dirq*4096))[dblk + tid];
    s_b[tid]  = (cb + dirq*1024)[dblk + tid];
  }

  // stage entire B tile: wave w stages col-group w across all 16 slices
  {
    const __bf16* bSrc = Bt + (size_t)(col0 + w*16 + r)*K + q*8;
    #pragma unroll
    for(int s=0;s<16;s++)
      gload_lds16(bSrc + s*32, Bs + (s*4 + w)*512);
  }

  f32x4 acc[2][4];
  #pragma unroll
  for(int i=0;i<2;i++)
    #pragma unroll
    for(int j=0;j<4;j++) acc[i][j] = (f32x4)0.f;

  const __bf16* aPtr[2];
  #pragma unroll
  for(int i=0;i<2;i++)
    aPtr[i] = A + (size_t)(row0 + w*32 + i*16 + r)*K + q*8;

  // prefetch slice 0 of A (in flight across the barrier)
  bf16x8 aCur[2], aNxt[2];
  #pragma unroll
  for(int i=0;i<2;i++) aCur[i] = *(const bf16x8*)(aPtr[i]);

  __syncthreads();   // single barrier: B tile resident

  #pragma unroll
  for(int s=0;s<16;s++){
    if(s<15){
      #pragma unroll
      for(int i=0;i<2;i++) aNxt[i] = *(const bf16x8*)(aPtr[i] + (s+1)*32);
    }
    bf16x8 bF[4];
    #pragma unroll
    for(int j=0;j<4;j++)
      bF[j] = *(const bf16x8*)(Bs + (s*4 + j)*512 + lane*8);
    #pragma unroll
    for(int i=0;i<2;i++)
      #pragma unroll
      for(int j=0;j<4;j++)
        acc[i][j] = __builtin_amdgcn_mfma_f32_16x16x32_bf16(bF[j], aCur[i], acc[i][j], 0, 0, 0);
    #pragma unroll
    for(int i=0;i<2;i++) aCur[i] = aNxt[i];
  }

  __bf16* ucbD = ucb + (size_t)dirq*NROWS*1024;
  __bf16* szD  = szb + (size_t)dirq*NROWS*1024;

  #pragma unroll
  for(int i=0;i<2;i++){
    int tok = row0 + w*32 + i*16 + r;      // token-in-seq == r
    #pragma unroll
    for(int j=0;j<4;j++){
      int nloc = j*16 + q*4;               // local feature base
      if(is_u){
        int f = nloc;
        int d = dblk + f;
        float vout[4];
        if(dirq==0){
          #pragma unroll
          for(int p=0;p<4;p++){
            float cur = acc[i][j][p];
            float m1 = __shfl_up(cur, 1, 64);
            float m2 = __shfl_up(cur, 2, 64);
            float m3 = __shfl_up(cur, 3, 64);
            float4 w4 = s_w4[f+p];
            float v = s_b[f+p] + w4.w*cur;
            v += (r>=1)? w4.z*m1 : 0.f;
            v += (r>=2)? w4.y*m2 : 0.f;
            v += (r>=3)? w4.x*m3 : 0.f;
            vout[p] = v;
          }
        } else {
          #pragma unroll
          for(int p=0;p<4;p++){
            float cur = acc[i][j][p];
            float p1 = __shfl_down(cur, 1, 64);
            float p2 = __shfl_down(cur, 2, 64);
            float p3 = __shfl_down(cur, 3, 64);
            float4 w4 = s_w4[f+p];
            float v = s_b[f+p] + w4.w*cur;
            v += (r<=14)? w4.z*p1 : 0.f;
            v += (r<=13)? w4.y*p2 : 0.f;
            v += (r<=12)? w4.x*p3 : 0.f;
            vout[p] = v;
          }
        }
        bf16x4 hv;
        #pragma unroll
        for(int p=0;p<4;p++) hv[p] = (__bf16)siluf(vout[p]);
        *(bf16x4*)(ucbD + (size_t)tok*1024 + d) = hv;
      } else {
        int dz = feat0 - 1024 + nloc;
        bf16x4 hv;
        #pragma unroll
        for(int p=0;p<4;p++) hv[p] = (__bf16)siluf(acc[i][j][p]);
        *(bf16x4*)(szD + (size_t)tok*1024 + dz) = hv;
      }
    }
  }
}

// ---------------------------------------------------------------------------
__global__ __launch_bounds__(256) void ln_pos_kernel(
    const float* __restrict__ in, const float* __restrict__ pb,
    const float* __restrict__ g, const float* __restrict__ bt,
    const float* __restrict__ pos, float* __restrict__ out)
{
  __shared__ float sred[4];
  int row = blockIdx.x; int l = row & 15; int tid = threadIdx.x;
  const float* ip = in + (size_t)row*512;
  float v0 = ip[tid] + pb[tid], v1 = ip[tid+256] + pb[tid+256];
  float s = block_reduce_sum(v0+v1, sred);
  float mean = s * (1.f/512.f);
  float d0 = v0-mean, d1 = v1-mean;
  float vs = block_reduce_sum(d0*d0+d1*d1, sred);
  float rstd = rsqrtf(vs*(1.f/512.f) + EPS);
  out[(size_t)row*512+tid]     = d0*rstd*g[tid]     + bt[tid]     + pos[l*512+tid];
  out[(size_t)row*512+tid+256] = d1*rstd*g[tid+256] + bt[tid+256] + pos[l*512+tid+256];
}

__global__ __launch_bounds__(256) void ln_bf16_kernel(
    const float* __restrict__ in, const float* __restrict__ g,
    const float* __restrict__ bt, __bf16* __restrict__ out)
{
  __shared__ float sred[4];
  int row = blockIdx.x; int tid = threadIdx.x;
  const float* ip = in + (size_t)row*512;
  float v0 = ip[tid], v1 = ip[tid+256];
  float s = block_reduce_sum(v0+v1, sred);
  float mean = s * (1.f/512.f);
  float d0 = v0-mean, d1 = v1-mean;
  float vs = block_reduce_sum(d0*d0+d1*d1, sred);
  float rstd = rsqrtf(vs*(1.f/512.f) + EPS);
  out[(size_t)row*512+tid]     = (__bf16)(d0*rstd*g[tid]     + bt[tid]);
  out[(size_t)row*512+tid+256] = (__bf16)(d1*rstd*g[tid+256] + bt[tid+256]);
}

__global__ __launch_bounds__(256) void ln_f32_kernel(
    const float* __restrict__ in, const float* __restrict__ g,
    const float* __restrict__ bt, float* __restrict__ out)
{
  __shared__ float sred[4];
  int row = blockIdx.x; int tid = threadIdx.x;
  const float* ip = in + (size_t)row*512;
  float v0 = ip[tid], v1 = ip[tid+256];
  float s = block_reduce_sum(v0+v1, sred);
  float mean = s * (1.f/512.f);
  float d0 = v0-mean, d1 = v1-mean;
  float vs = block_reduce_sum(d0*d0+d1*d1, sred);
  float rstd = rsqrtf(vs*(1.f/512.f) + EPS);
  out[(size_t)row*512+tid]     = d0*rstd*g[tid]     + bt[tid];
  out[(size_t)row*512+tid+256] = d1*rstd*g[tid+256] + bt[tid+256];
}

// ---------------------------------------------------------------------------
// selective scan, both dirs (gridDim.y=8: dir = y>>2). dt/uc/sz/proj bf16,
// token order. gb out: [row][2048] bf16 K-concat for out_proj.
// ---------------------------------------------------------------------------
__global__ __launch_bounds__(256) void scan_kernel(
    const __bf16* __restrict__ dtb, const __bf16* __restrict__ ucb,
    const __bf16* __restrict__ projb, const __bf16* __restrict__ szb,
    const float* __restrict__ A_log, const float* __restrict__ Dskip,
    __bf16* __restrict__ gb)
{
  int b = blockIdx.x;
  int dirq = blockIdx.y >> 2;
  int d = (blockIdx.y & 3)*256 + threadIdx.x;
  const __bf16* dtp = dtb + (size_t)dirq*NROWS*1024;
  const __bf16* ucp = ucb + (size_t)dirq*NROWS*1024;
  const __bf16* prp = projb + (size_t)dirq*NROWS*64;
  const __bf16* szp = szb  + (size_t)dirq*NROWS*1024;
  const float*  Alp = A_log + (size_t)dirq*1024*16;
  float Dv = Dskip[dirq*1024 + d];
  __shared__ float sB[16][16], sC[16][16];
  {
    int s = threadIdx.x >> 4, n = threadIdx.x & 15;
    int tok = dirq ? 15-s : s;
    sB[s][n] = (float)prp[(size_t)(b*16+tok)*64 + 32 + n];
    sC[s][n] = (float)prp[(size_t)(b*16+tok)*64 + 48 + n];
  }
  __syncthreads();
  float a[16], hst[16];
  #pragma unroll
  for(int n=0;n<16;n++){ a[n] = -__expf(Alp[d*16+n]); hst[n]=0.f; }
  for(int s=0;s<16;s++){
    int tok = dirq ? 15-s : s;
    size_t o = (size_t)(b*16+tok)*1024 + d;
    float dtv = (float)dtp[o];
    float ucv = (float)ucp[o];
    float dtu = dtv*ucv;
    float y = 0.f;
    #pragma unroll
    for(int n=0;n<16;n++){
      hst[n] = __expf(dtv*a[n])*hst[n] + dtu*sB[s][n];
      y += hst[n]*sC[s][n];
    }
    float zs = (float)szp[o];
    gb[(size_t)(b*16+tok)*2048 + dirq*1024 + d] = (__bf16)((y + ucv*Dv) * zs);
  }
}

// ---------------------------------------------------------------------------
extern "C" void kernel_launch(void* const* d_in, const int* in_sizes, int n_in,
                              void* d_out, int out_size, void* d_ws, size_t ws_size,
                              hipStream_t stream) {
  (void)in_sizes; (void)n_in; (void)out_size; (void)ws_size;
  const float* x         = (const float*)d_in[0];
  const float* bn_gamma  = (const float*)d_in[1];
  const float* bn_beta   = (const float*)d_in[2];
  const float* bn_mean   = (const float*)d_in[3];
  const float* bn_var    = (const float*)d_in[4];
  const float* patch_w   = (const float*)d_in[5];
  const float* patch_b   = (const float*)d_in[6];
  const float* ln_pg     = (const float*)d_in[7];
  const float* ln_pb     = (const float*)d_in[8];
  const float* pos       = (const float*)d_in[9];
  const float* blk_ln_g  = (const float*)d_in[10];
  const float* blk_ln_b  = (const float*)d_in[11];
  const float* in_proj_w = (const float*)d_in[12];
  const float* conv_w    = (const float*)d_in[13];
  const float* conv_b    = (const float*)d_in[14];
  const float* x_proj_w  = (const float*)d_in[15];
  const float* dt_proj_w = (const float*)d_in[16];
  const float* dt_proj_b = (const float*)d_in[17];
  const float* A_log     = (const float*)d_in[18];
  const float* Dskip     = (const float*)d_in[19];
  const float* out_proj_w= (const float*)d_in[20];
  const float* fin_g     = (const float*)d_in[21];
  const float* fin_b     = (const float*)d_in[22];

  char* p = (char*)d_ws;
  float*  h    = (float*)p;  p += (size_t)NROWS*512*4;      // 8 MB
  __bf16* hnb  = (__bf16*)p; p += (size_t)NROWS*512*2;      // 4 MB
  __bf16* ucb2 = (__bf16*)p; p += (size_t)2*NROWS*1024*2;   // 16 MB
  __bf16* szb2 = (__bf16*)p; p += (size_t)2*NROWS*1024*2;   // 16 MB
  __bf16* dtb2 = (__bf16*)p; p += (size_t)2*NROWS*1024*2;   // 16 MB
  __bf16* gbK  = (__bf16*)p; p += (size_t)NROWS*2048*2;     // 16 MB (also patch f32 scratch)
  __bf16* projb2=(__bf16*)p; p += (size_t)2*NROWS*64*2;     // 1 MB
  __bf16* wtin = (__bf16*)p; p += (size_t)4*2048*512*2;     // 8 MB
  __bf16* wtoutK=(__bf16*)p; p += (size_t)2*512*2048*2;     // 4 MB
  __bf16* wtx  = (__bf16*)p; p += (size_t)4*64*1024*2;      // 0.5 MB
  __bf16* wdtT = (__bf16*)p; p += (size_t)4*1024*32*2;      // 0.25 MB
  __bf16* Abuf = (__bf16*)p; p += (size_t)NROWS*KPAD*2;     // 0.75 MB
  __bf16* pwb  = (__bf16*)p; p += (size_t)512*KPAD*2;       // 96 KB

  // ---- weight prep ----
  transpose_bf16_kernel<<<dim3(64, 16, 4), dim3(32,8), 0, stream>>>(
      in_proj_w, wtin, 512, 2048);
  transpose_outw_kernel<<<dim3(16, 32, 4), dim3(32,8), 0, stream>>>(
      out_proj_w, wtoutK);
  transpose_bf16_kernel<<<dim3(2, 32, 4), dim3(32,8), 0, stream>>>(
      x_proj_w, wtx, 1024, 64);
  transpose_bf16_kernel<<<dim3(32, 1, 4), dim3(32,8), 0, stream>>>(
      dt_proj_w, wdtT, 32, 1024);
  cast_pad_pw_kernel<<<(512*KPAD + 255)/256, 256, 0, stream>>>(patch_w, pwb);

  // ---- patch embed ----
  bn_patchify_kernel<<<(NROWS*KPAD)/256, 256, 0, stream>>>(
      x, bn_gamma, bn_beta, bn_mean, bn_var, Abuf);
  mfma_gemm<128,128,32,0,0><<<dim3(4, 32, 1), 256, 0, stream>>>(
      Abuf, pwb, (float*)gbK, nullptr, nullptr, 512, KPAD, KPAD, KPAD, 0,0,0,0);
  ln_pos_kernel<<<NROWS, 256, 0, stream>>>((float*)gbK, patch_b, ln_pg, ln_pb, pos, h);

  for(int i=0;i<2;i++){
    ln_bf16_kernel<<<NROWS, 256, 0, stream>>>(h, blk_ln_g + i*512, blk_ln_b + i*512, hnb);
    // in_proj both dirs + conv + silu -> ucb2/szb2 (bf16, token order)
    mfma_inproj_conv<<<dim3(64, 32), 256, 0, stream>>>(
        hnb, wtin + (size_t)i*4096*512, conv_w + (size_t)i*2*4096,
        conv_b + (size_t)i*2*1024, ucb2, szb2);
    // x_proj (z=2 dirs): projb bf16 only
    mfma_gemm<64,64,64,0,3><<<dim3(1, 64, 2), 256, 0, stream>>>(
        ucb2, wtx + (size_t)i*2*64*1024, nullptr, projb2, nullptr,
        64, 1024, 1024, 1024,
        (size_t)NROWS*1024, (size_t)64*1024, (size_t)NROWS*64, 0);
    // dt = softplus(dtr @ Wdt + bias) -> bf16
    mfma_gemm<64,64,32,0,2><<<dim3(16, 64, 2), 256, 0, stream>>>(
        projb2, wdtT + (size_t)i*2*1024*32, nullptr, dtb2, dt_proj_b + (size_t)i*2*1024,
        1024, 32, 64, 32,
        (size_t)NROWS*64, (size_t)1024*32, (size_t)NROWS*1024, 1024);
    // scan both dirs -> gbK [row][2048]
    scan_kernel<<<dim3(BB, 8), 256, 0, stream>>>(
        dtb2, ucb2, projb2, szb2, A_log + (size_t)i*2*1024*16,
        Dskip + (size_t)i*2*1024, gbK);
    // out_proj both dirs, K=2048, accumulate into h
    mfma_gemm<64,64,64,1,0><<<dim3(8, 64, 1), 256, 0, stream>>>(
        gbK, wtoutK + (size_t)i*512*2048, h, nullptr, nullptr,
        512, 2048, 2048, 2048, 0,0,0,0);
  }
  ln_f32_kernel<<<NROWS, 256, 0, stream>>>(h, fin_g, fin_b, (float*)d_out);
}